// Round 3
// baseline (4524.150 us; speedup 1.0000x reference)
//
#include <hip/hip_runtime.h>
#include <hip/hip_bf16.h>
#include <stdint.h>
#include <math.h>

typedef __hip_bfloat16 bf16;
typedef short s16x8 __attribute__((ext_vector_type(8)));
typedef float f32x4 __attribute__((ext_vector_type(4)));

#define SCALE_QK 0.03608439182435161f   /* 768^-0.5 (ref scales by n_embd^-0.5) */
#define NEG_BIG  -1.0e30f

// ===========================================================================
// GEMM: C[M,N] = A[M,K](bf16, row-major) * BT[N,K](bf16, row-major)^T
// 128x128 tile, 4 waves (2x2), each wave 64x64 via 4x4 mfma_f32_16x16x32_bf16.
// Register-staged LDS (global->reg->ds_write) — correctness-first.
// ===========================================================================
enum { EPI_BF16 = 0, EPI_GELU = 1, EPI_RES = 2, EPI_HEAD = 3 };

template <int EPI>
__global__ __launch_bounds__(256)
void gemm_bt(const bf16* __restrict__ A, const bf16* __restrict__ BT,
             const float* __restrict__ bias, float* Cf, bf16* Cb,
             int M, int N, int K, int Nreal)
{
  __shared__ __align__(16) bf16 As[128 * 32];
  __shared__ __align__(16) bf16 Bs[128 * 32];
  const int tid = threadIdx.x;
  const int w = tid >> 6, l = tid & 63;
  const int lo = l & 15, hi = l >> 4;
  const int wm = (w & 1) * 64, wn = (w >> 1) * 64;
  const long row0 = (long)blockIdx.y * 128;
  const long col0 = (long)blockIdx.x * 128;

  // chunk c (0..511) covers LDS elements [8c,8c+8) == tile row c>>2, k-cols (c&3)*8..+8
  const int c0 = tid, c1 = tid + 256;
  const bf16* a0 = A + (row0 + (c0 >> 2)) * K + (c0 & 3) * 8;
  const bf16* a1 = A + (row0 + (c1 >> 2)) * K + (c1 & 3) * 8;
  const bf16* b0 = BT + (col0 + (c0 >> 2)) * K + (c0 & 3) * 8;
  const bf16* b1 = BT + (col0 + (c1 >> 2)) * K + (c1 & 3) * 8;

  const f32x4 zero4 = {0.f, 0.f, 0.f, 0.f};
  f32x4 acc[4][4];
#pragma unroll
  for (int m = 0; m < 4; ++m)
#pragma unroll
    for (int n = 0; n < 4; ++n) acc[m][n] = zero4;

  for (int kt = 0; kt < K; kt += 32) {
    const s16x8 ra0 = *(const s16x8*)(a0 + kt);
    const s16x8 ra1 = *(const s16x8*)(a1 + kt);
    const s16x8 rb0 = *(const s16x8*)(b0 + kt);
    const s16x8 rb1 = *(const s16x8*)(b1 + kt);
    __syncthreads();                       // prev iteration's LDS reads done
    *(s16x8*)&As[c0 * 8] = ra0;
    *(s16x8*)&As[c1 * 8] = ra1;
    *(s16x8*)&Bs[c0 * 8] = rb0;
    *(s16x8*)&Bs[c1 * 8] = rb1;
    __syncthreads();                       // writes visible
    s16x8 af[4], bfr[4];
#pragma unroll
    for (int m = 0; m < 4; ++m)
      af[m] = *(const s16x8*)&As[(wm + m * 16 + lo) * 32 + hi * 8];
#pragma unroll
    for (int n = 0; n < 4; ++n)
      bfr[n] = *(const s16x8*)&Bs[(wn + n * 16 + lo) * 32 + hi * 8];
#pragma unroll
    for (int m = 0; m < 4; ++m)
#pragma unroll
      for (int n = 0; n < 4; ++n)
        acc[m][n] = __builtin_amdgcn_mfma_f32_16x16x32_bf16(af[m], bfr[n], acc[m][n], 0, 0, 0);
  }

#pragma unroll
  for (int m = 0; m < 4; ++m) {
#pragma unroll
    for (int n = 0; n < 4; ++n) {
      const long col = col0 + wn + n * 16 + lo;
#pragma unroll
      for (int r = 0; r < 4; ++r) {
        const long row = row0 + wm + m * 16 + hi * 4 + r;
        float v = acc[m][n][r];
        if constexpr (EPI == EPI_BF16) {
          Cb[row * N + col] = __float2bfloat16(v);
        } else if constexpr (EPI == EPI_GELU) {
          v += bias[col];
          v = 0.5f * v * (1.f + erff(v * 0.70710678118654752f));
          Cb[row * N + col] = __float2bfloat16(v);
        } else if constexpr (EPI == EPI_RES) {
          Cf[row * N + col] += v + bias[col];
        } else {  // EPI_HEAD
          if (col < Nreal) Cf[row * Nreal + col] = v + bias[col];
        }
      }
    }
  }
}

// ===========================================================================
// Flash attention, causal. Block = 4 waves, 128 q-rows per block (32 per
// wave), kv tiles of 64. qkv layout [B*T, 2304] bf16 (q|k|v, head-major 64).
// K and V both staged LINEARLY [j][64] in LDS; V b-fragments read as 8
// scalars down a column (4-way bank conflict only) — correctness-first.
// ===========================================================================
__global__ __launch_bounds__(256)
void attn_kernel(const bf16* __restrict__ qkv, bf16* __restrict__ o)
{
  __shared__ __align__(16) bf16 Kl[64 * 64];
  __shared__ __align__(16) bf16 Vl[64 * 64];
  __shared__ __align__(16) bf16 Pl[4][32 * 64];
  const int tid = threadIdx.x;
  const int w = tid >> 6, l = tid & 63;
  const int lo = l & 15, hi = l >> 4;
  const int q0 = blockIdx.x * 128;
  const int b = blockIdx.y / 12, h = blockIdx.y % 12;
  const int wq0 = q0 + w * 32;
  const bf16* base = qkv + (long)b * 1024 * 2304;

  // Q fragments (rows wq0..wq0+31, all of d=64)
  s16x8 qf[2][2];
#pragma unroll
  for (int m = 0; m < 2; ++m)
#pragma unroll
    for (int ks = 0; ks < 2; ++ks)
      qf[m][ks] = *(const s16x8*)(base + (long)(wq0 + m * 16 + lo) * 2304 + h * 64 + ks * 32 + hi * 8);

  const f32x4 zero4 = {0.f, 0.f, 0.f, 0.f};
  f32x4 oacc[2][4];
  float mst[2][4], lst[2][4];
#pragma unroll
  for (int m = 0; m < 2; ++m) {
#pragma unroll
    for (int n = 0; n < 4; ++n) oacc[m][n] = zero4;
#pragma unroll
    for (int r = 0; r < 4; ++r) { mst[m][r] = -3.0e38f; lst[m][r] = 0.f; }
  }

  // chunk c (0..511): row c>>3, cols (c&7)*8..+8 of a [64][64] tile
  const int cB = tid + 256;

  const int nt = (q0 + 128) / 64;
  for (int t = 0; t < nt; ++t) {
    const int j0 = t * 64;
    const s16x8 rk0 = *(const s16x8*)(base + (long)(j0 + (tid >> 3)) * 2304 +  768 + h * 64 + (tid & 7) * 8);
    const s16x8 rk1 = *(const s16x8*)(base + (long)(j0 + (cB  >> 3)) * 2304 +  768 + h * 64 + (cB  & 7) * 8);
    const s16x8 rv0 = *(const s16x8*)(base + (long)(j0 + (tid >> 3)) * 2304 + 1536 + h * 64 + (tid & 7) * 8);
    const s16x8 rv1 = *(const s16x8*)(base + (long)(j0 + (cB  >> 3)) * 2304 + 1536 + h * 64 + (cB  & 7) * 8);
    __syncthreads();                       // prev iteration's LDS reads done
    *(s16x8*)&Kl[tid * 8] = rk0;
    *(s16x8*)&Kl[cB  * 8] = rk1;
    *(s16x8*)&Vl[tid * 8] = rv0;
    *(s16x8*)&Vl[cB  * 8] = rv1;
    __syncthreads();                       // writes visible

    if (j0 <= wq0 + 31) {   // wave-uniform causal skip
      // S = Q K^T
      f32x4 s[2][4];
#pragma unroll
      for (int m = 0; m < 2; ++m)
#pragma unroll
        for (int n = 0; n < 4; ++n) s[m][n] = zero4;
#pragma unroll
      for (int ks = 0; ks < 2; ++ks) {
        s16x8 kf[4];
#pragma unroll
        for (int n = 0; n < 4; ++n)
          kf[n] = *(const s16x8*)&Kl[(n * 16 + lo) * 64 + ks * 32 + hi * 8];
#pragma unroll
        for (int m = 0; m < 2; ++m)
#pragma unroll
          for (int n = 0; n < 4; ++n)
            s[m][n] = __builtin_amdgcn_mfma_f32_16x16x32_bf16(qf[m][ks], kf[n], s[m][n], 0, 0, 0);
      }
      // scale + causal mask (C layout: row q = m*16+hi*4+r, col j = n*16+lo)
      const bool edge = (j0 + 63 > wq0);
#pragma unroll
      for (int m = 0; m < 2; ++m)
#pragma unroll
        for (int n = 0; n < 4; ++n) {
          const int j = j0 + n * 16 + lo;
#pragma unroll
          for (int r = 0; r < 4; ++r) {
            float v = s[m][n][r] * SCALE_QK;
            if (edge && j > wq0 + m * 16 + hi * 4 + r) v = NEG_BIG;
            s[m][n][r] = v;
          }
        }
      // online softmax (row q lives on 16 lanes: lanes with same hi*4+r)
#pragma unroll
      for (int m = 0; m < 2; ++m)
#pragma unroll
        for (int r = 0; r < 4; ++r) {
          float x = fmaxf(fmaxf(s[m][0][r], s[m][1][r]), fmaxf(s[m][2][r], s[m][3][r]));
          x = fmaxf(x, __shfl_xor(x, 1));
          x = fmaxf(x, __shfl_xor(x, 2));
          x = fmaxf(x, __shfl_xor(x, 4));
          x = fmaxf(x, __shfl_xor(x, 8));
          const float mn = fmaxf(mst[m][r], x);
          const float corr = __expf(mst[m][r] - mn);
          mst[m][r] = mn;
          float rs = 0.f;
#pragma unroll
          for (int n = 0; n < 4; ++n) {
            float p = __expf(s[m][n][r] - mn);
            s[m][n][r] = p;
            rs += p;
          }
          rs += __shfl_xor(rs, 1);
          rs += __shfl_xor(rs, 2);
          rs += __shfl_xor(rs, 4);
          rs += __shfl_xor(rs, 8);
          lst[m][r] = lst[m][r] * corr + rs;
#pragma unroll
          for (int n = 0; n < 4; ++n) oacc[m][n][r] *= corr;
        }
      // P: C-layout -> A-layout via per-wave LDS round trip
#pragma unroll
      for (int m = 0; m < 2; ++m)
#pragma unroll
        for (int n = 0; n < 4; ++n)
#pragma unroll
          for (int r = 0; r < 4; ++r)
            Pl[w][(m * 16 + hi * 4 + r) * 64 + n * 16 + lo] = __float2bfloat16(s[m][n][r]);
      s16x8 pa[2][2];
#pragma unroll
      for (int m = 0; m < 2; ++m)
#pragma unroll
        for (int ks = 0; ks < 2; ++ks)
          pa[m][ks] = *(const s16x8*)&Pl[w][(m * 16 + lo) * 64 + ks * 32 + hi * 8];
      // O += P V : B-fragment of V read as 8 scalars down column d=n*16+lo
      // (same contiguous-k map as pa -> k-permutation cancellation-safe)
#pragma unroll
      for (int ks = 0; ks < 2; ++ks)
#pragma unroll
        for (int n = 0; n < 4; ++n) {
          s16x8 vf;
#pragma unroll
          for (int j = 0; j < 8; ++j)
            vf[j] = *(const short*)&Vl[(ks * 32 + hi * 8 + j) * 64 + n * 16 + lo];
#pragma unroll
          for (int m = 0; m < 2; ++m)
            oacc[m][n] = __builtin_amdgcn_mfma_f32_16x16x32_bf16(pa[m][ks], vf, oacc[m][n], 0, 0, 0);
        }
    }
  }
  // epilogue: normalize and store (o layout [B*T, 768], head-major)
#pragma unroll
  for (int m = 0; m < 2; ++m)
#pragma unroll
    for (int n = 0; n < 4; ++n)
#pragma unroll
      for (int r = 0; r < 4; ++r) {
        const int q = wq0 + m * 16 + hi * 4 + r;
        o[(long)(b * 1024 + q) * 768 + h * 64 + n * 16 + lo] =
            __float2bfloat16(oacc[m][n][r] / lst[m][r]);
      }
}

// ===========================================================================
// helpers: idx-dtype detect, embed, layernorm, fp32->bf16 transpose / convert
// ===========================================================================
__global__ void detect_idx(const int* __restrict__ idx, int* __restrict__ flag)
{
  const int t = threadIdx.x;                 // 64 threads, 1 wave
  const int v = idx[2 * t + 1];
  const unsigned long long nz = __ballot(v != 0);
  if (t == 0) flag[0] = (nz == 0ull) ? 1 : 0;
}

__global__ __launch_bounds__(192)
void embed_kernel(const int* __restrict__ idx, const float* __restrict__ tok,
                  const float* __restrict__ pos, float* __restrict__ x,
                  const int* __restrict__ flag)
{
  const int row = blockIdx.x;            // b*T + t
  const int t = row & 1023;
  const int id = flag[0] ? idx[2 * row] : idx[row];   // int64 low word vs int32
  const int e = threadIdx.x * 4;
  const float4 a = *(const float4*)&tok[(long)id * 768 + e];
  const float4 p = *(const float4*)&pos[(long)t * 768 + e];
  float4 r; r.x = a.x + p.x; r.y = a.y + p.y; r.z = a.z + p.z; r.w = a.w + p.w;
  *(float4*)&x[(long)row * 768 + e] = r;
}

__global__ __launch_bounds__(256)
void ln_kernel(const float* __restrict__ x, const float* __restrict__ g,
               const float* __restrict__ bt, bf16* __restrict__ out)
{
  const int row = blockIdx.x, tid = threadIdx.x;
  const float* xr = x + (long)row * 768;
  const float v0 = xr[tid], v1 = xr[tid + 256], v2 = xr[tid + 512];
  float s = v0 + v1 + v2;
  float q = v0 * v0 + v1 * v1 + v2 * v2;
#pragma unroll
  for (int o = 32; o > 0; o >>= 1) { s += __shfl_down(s, o); q += __shfl_down(q, o); }
  __shared__ float sh[8];
  const int w = tid >> 6;
  if ((tid & 63) == 0) { sh[w] = s; sh[4 + w] = q; }
  __syncthreads();
  s = sh[0] + sh[1] + sh[2] + sh[3];
  q = sh[4] + sh[5] + sh[6] + sh[7];
  const float mu = s * (1.f / 768.f);
  const float var = q * (1.f / 768.f) - mu * mu;
  const float rs = rsqrtf(var + 1e-8f);
  bf16* orow = out + (long)row * 768;
  orow[tid]       = __float2bfloat16((v0 - mu) * rs * g[tid] + bt[tid]);
  orow[tid + 256] = __float2bfloat16((v1 - mu) * rs * g[tid + 256] + bt[tid + 256]);
  orow[tid + 512] = __float2bfloat16((v2 - mu) * rs * g[tid + 512] + bt[tid + 512]);
}

// out[z][c][r] (bf16) = in[z][r][c] (fp32); R mult of 64; pads c>=Creal with 0.
__global__ __launch_bounds__(256)
void transpose_conv(const float* __restrict__ in, bf16* __restrict__ out,
                    int R, int Creal, long inStride, long outStride)
{
  __shared__ float tile[64][65];
  const int tx = threadIdx.x & 63, ty = threadIdx.x >> 6;
  const long z = blockIdx.z;
  const int c0 = blockIdx.x * 64, r0 = blockIdx.y * 64;
  const float* ip = in + z * inStride;
  bf16* op = out + z * outStride;
#pragma unroll
  for (int p = 0; p < 16; ++p) {
    const int r = p * 4 + ty;
    const int c = c0 + tx;
    tile[r][tx] = (c < Creal) ? ip[(long)(r0 + r) * Creal + c] : 0.f;
  }
  __syncthreads();
#pragma unroll
  for (int p = 0; p < 16; ++p) {
    const int cc = p * 4 + ty;
    op[(long)(c0 + cc) * R + r0 + tx] = __float2bfloat16(tile[tx][cc]);
  }
}

__global__ __launch_bounds__(256)
void convert_k(const float* __restrict__ in, bf16* __restrict__ out, int n)
{
  const int i = (blockIdx.x * 256 + threadIdx.x) * 4;
  if (i < n) {
    const float4 v = *(const float4*)&in[i];
    out[i]     = __float2bfloat16(v.x);
    out[i + 1] = __float2bfloat16(v.y);
    out[i + 2] = __float2bfloat16(v.z);
    out[i + 3] = __float2bfloat16(v.w);
  }
}

// ===========================================================================
extern "C" void kernel_launch(void* const* d_in, const int* in_sizes, int n_in,
                              void* d_out, int out_size, void* d_ws, size_t ws_size,
                              hipStream_t stream)
{
  (void)in_sizes; (void)n_in; (void)out_size; (void)ws_size;
  const int*   idx   = (const int*)d_in[0];
  const float* tok   = (const float*)d_in[1];
  const float* pos   = (const float*)d_in[2];
  const float* wq    = (const float*)d_in[3];
  const float* wk    = (const float*)d_in[4];
  const float* wv    = (const float*)d_in[5];
  const float* projw = (const float*)d_in[6];
  const float* projb = (const float*)d_in[7];
  const float* ln1g  = (const float*)d_in[8];
  const float* ln1b  = (const float*)d_in[9];
  const float* ln2g  = (const float*)d_in[10];
  const float* ln2b  = (const float*)d_in[11];
  const float* w1    = (const float*)d_in[12];
  const float* b1    = (const float*)d_in[13];
  const float* w2    = (const float*)d_in[14];
  const float* b2    = (const float*)d_in[15];
  const float* lnfg  = (const float*)d_in[16];
  const float* lnfb  = (const float*)d_in[17];
  const float* headw = (const float*)d_in[18];
  const float* headb = (const float*)d_in[19];
  float* out = (float*)d_out;

  char* ws = (char*)d_ws;
  size_t off = 0;
  auto alloc = [&](size_t bytes) -> void* {
    void* p = ws + off; off += (bytes + 255) & ~(size_t)255; return p;
  };
  int*   iflag  = (int*)  alloc(256);
  float* x      = (float*)alloc(4096ull * 768 * 4);
  bf16*  xn     = (bf16*) alloc(4096ull * 768 * 2);
  bf16*  qkvb   = (bf16*) alloc(4096ull * 2304 * 2);
  bf16*  ob     = (bf16*) alloc(4096ull * 768 * 2);
  bf16*  hb     = (bf16*) alloc(4096ull * 3072 * 2);
  bf16*  WqkvT  = (bf16*) alloc(2304ull * 768 * 2);
  bf16*  WprojT = (bf16*) alloc(768ull * 768 * 2);
  bf16*  W1T    = (bf16*) alloc(3072ull * 768 * 2);
  bf16*  W2T    = (bf16*) alloc(768ull * 3072 * 2);
  bf16*  headT  = (bf16*) alloc(50304ull * 768 * 2);   // padded to 393*128 rows

  detect_idx<<<1, 64, 0, stream>>>(idx, iflag);
  // head_w [768][50257] -> headT [50304][768] (once)
  transpose_conv<<<dim3(786, 12, 1), 256, 0, stream>>>(headw, headT, 768, 50257, 0, 0);
  embed_kernel<<<4096, 192, 0, stream>>>(idx, tok, pos, x, iflag);

  for (int l = 0; l < 12; ++l) {
    const size_t hOff = (size_t)l * 12 * 768 * 64;
    // per-head [768][64] -> rows h*64.. of WqkvT (q), +768*768 (k), +1536*768 (v)
    transpose_conv<<<dim3(1, 12, 12), 256, 0, stream>>>(wq + hOff, WqkvT,              768, 64, 49152, 49152);
    transpose_conv<<<dim3(1, 12, 12), 256, 0, stream>>>(wk + hOff, WqkvT + 768  * 768, 768, 64, 49152, 49152);
    transpose_conv<<<dim3(1, 12, 12), 256, 0, stream>>>(wv + hOff, WqkvT + 1536 * 768, 768, 64, 49152, 49152);
    convert_k<<<576, 256, 0, stream>>>(projw + (size_t)l * 768 * 768, WprojT, 768 * 768);
    transpose_conv<<<dim3(48, 12, 1), 256, 0, stream>>>(w1 + (size_t)l * 768 * 3072, W1T, 768, 3072, 0, 0);
    transpose_conv<<<dim3(12, 48, 1), 256, 0, stream>>>(w2 + (size_t)l * 3072 * 768, W2T, 3072, 768, 0, 0);

    ln_kernel<<<4096, 256, 0, stream>>>(x, ln1g + l * 768, ln1b + l * 768, xn);
    gemm_bt<EPI_BF16><<<dim3(18, 32), 256, 0, stream>>>(xn, WqkvT, nullptr, nullptr, qkvb, 4096, 2304, 768, 2304);
    attn_kernel<<<dim3(8, 48), 256, 0, stream>>>(qkvb, ob);
    gemm_bt<EPI_RES><<<dim3(6, 32), 256, 0, stream>>>(ob, WprojT, projb + l * 768, x, nullptr, 4096, 768, 768, 768);
    ln_kernel<<<4096, 256, 0, stream>>>(x, ln2g + l * 768, ln2b + l * 768, xn);
    gemm_bt<EPI_GELU><<<dim3(24, 32), 256, 0, stream>>>(xn, W1T, b1 + (size_t)l * 3072, nullptr, hb, 4096, 3072, 768, 3072);
    gemm_bt<EPI_RES><<<dim3(6, 32), 256, 0, stream>>>(hb, W2T, b2 + l * 768, x, nullptr, 4096, 768, 3072, 768);
  }

  ln_kernel<<<4096, 256, 0, stream>>>(x, lnfg, lnfb, xn);
  gemm_bt<EPI_HEAD><<<dim3(393, 32), 256, 0, stream>>>(xn, headT, headb, out, nullptr, 4096, 50304, 768, 50257);
}